// Round 9
// baseline (424.298 us; speedup 1.0000x reference)
//
#include <hip/hip_runtime.h>
#include <hip/hip_bf16.h>

// 3-layer GCN. Round 18: R17 (best, 316.7us) + degree-uniform gather blocks.
// R17 showed fused-gather cost over pure gather (~11us) is degree skew:
// wave runs to max-degree of its 4 nodes (E[max4 Poi(16)]=22.7 vs 16),
// block barrier waits on max of 16 (25.4). Fix: counting-sort nodes by
// degree (histogram folded into bucket_place; 1-block scan; tiny placement
// kernel -> perm[]). Fused gathers walk perm order: every wave/block has
// ~uniform degree. Row identity preserved via perm lookups in epilogue.
// Also: memset + convw merged into one leading kernel (zero-fill blocks).
//   convw(zero+conv) -> bincount8 -> bucket_scan8 -> bin_scatter ->
//   bucket_place(+deg hist) -> scanD -> dperm -> gemm1 -> fused1 -> fused2
// Requires N <= 131072 (NB <= 1024) and N < 2^25 for packing.

#define FEAT 128
#define OUTF 64
#define BSH 7                 // 128 nodes per bucket
#define BNODES (1 << BSH)
#define SCHUNK_SH 12          // 4096 edges per bin_scatter block
#define SCHUNK (1 << SCHUNK_SH)
#define NREP 8                // cursor replicas per bucket
#define GDEPTH 16             // gather unroll depth (rows in flight per group)

typedef __attribute__((ext_vector_type(8))) short short8;
typedef __attribute__((ext_vector_type(4))) float f32x4;

__device__ __forceinline__ unsigned short bf16_rn(float f) {
    unsigned int u = __float_as_uint(f);
    u += 0x7FFFu + ((u >> 16) & 1u);   // round-to-nearest-even
    return (unsigned short)(u >> 16);
}
__device__ __forceinline__ float bf16_lo(unsigned int u) { return __uint_as_float(u << 16); }
__device__ __forceinline__ float bf16_hi(unsigned int u) { return __uint_as_float(u & 0xFFFF0000u); }

// ---- k0: weight convert + zero bcnt8/dhist8 (replaces memset dispatch) ----
// blocks 0..159: conv; 160..191: zero dhist8; 192..223: zero bcnt8.
__global__ __launch_bounds__(256) void convw_kernel(
        const float* __restrict__ W1, const float* __restrict__ W2,
        const float* __restrict__ Wout,
        __hip_bfloat16* __restrict__ W1t, __hip_bfloat16* __restrict__ W2t,
        __hip_bfloat16* __restrict__ WoutT,
        int* __restrict__ bcnt8, int* __restrict__ dhist8) {
    int bx = blockIdx.x;
    if (bx >= 160) {
        int* z = (bx < 192) ? dhist8 : bcnt8;
        z[((bx & 31) << 8) | threadIdx.x] = 0;   // 32 blocks x 256 = 8192
        return;
    }
    int idx = bx * 256 + threadIdx.x;
    if (idx < 2 * FEAT * FEAT) {
        int which = idx >> 14;               // /16384
        int r = idx & (FEAT * FEAT - 1);
        int n = r >> 7, k = r & 127;
        const float* W = which ? W2 : W1;
        unsigned short* Wt = (unsigned short*)(which ? W2t : W1t);
        Wt[r] = bf16_rn(W[k * FEAT + n]);
    } else if (idx < 2 * FEAT * FEAT + OUTF * FEAT) {
        int r = idx - 2 * FEAT * FEAT;
        int n = r >> 7, k = r & 127;         // n<64 out-col, k<128 hidden
        ((unsigned short*)WoutT)[r] = bf16_rn(Wout[k * OUTF + n]);
    }
}

// ---- k1: per-(bucket,replica) edge counts; replica = chunk&7 ----
__global__ __launch_bounds__(256) void bincount8_kernel(
        const int* __restrict__ dst, int* __restrict__ bcnt8, int E, int NB) {
    __shared__ int h[8192];
    int t = threadIdx.x;
    int nb8 = NB * NREP;
    for (int i = t; i < nb8; i += 256) h[i] = 0;
    __syncthreads();
    int stride = gridDim.x * 256;
    for (int e = blockIdx.x * 256 + t; e < E; e += stride) {
        int rep = (e >> SCHUNK_SH) & (NREP - 1);
        atomicAdd(&h[((dst[e] >> BSH) << 3) | rep], 1);
    }
    __syncthreads();
    for (int i = t; i < nb8; i += 256)
        if (h[i]) atomicAdd(&bcnt8[i], h[i]);
}

// ---- k2: exclusive scan of bcnt8[NB*8] -> bcur8 (absolute positions), bbase ----
__global__ __launch_bounds__(1024) void bucket_scan8_kernel(
        const int* __restrict__ bcnt8, int* __restrict__ bcur8,
        int* __restrict__ bbase, int NB, int E) {
    int t = threadIdx.x;
    int nb8 = NB * NREP;
    int base = t * 8;
    int v[8];
    #pragma unroll
    for (int i = 0; i < 8; ++i) v[i] = (base + i < nb8) ? bcnt8[base + i] : 0;
    int local = 0;
    #pragma unroll
    for (int i = 0; i < 8; ++i) local += v[i];
    int lane = t & 63, wv = t >> 6;
    int x = local;
    #pragma unroll
    for (int o = 1; o < 64; o <<= 1) {
        int y = __shfl_up(x, o);
        if (lane >= o) x += y;
    }
    __shared__ int wsum[16];
    if (lane == 63) wsum[wv] = x;
    __syncthreads();
    int woff = 0;
    for (int i = 0; i < wv; ++i) woff += wsum[i];
    int run = woff + x - local;
    #pragma unroll
    for (int i = 0; i < 8; ++i) {
        int g = base + i;
        if (g < nb8) {
            bcur8[g] = run;
            if ((g & (NREP - 1)) == 0) bbase[g >> 3] = run;
        }
        run += v[i];
    }
    if (t == 0) bbase[NB] = E;
}

// ---- k3: two-phase scatter of packed (src | dlocal<<25), bucket-major ----
__global__ __launch_bounds__(256) void bin_scatter_kernel(
        const int* __restrict__ src, const int* __restrict__ dst,
        int* __restrict__ bcur8, unsigned int* __restrict__ staged,
        int E, int NB) {
    __shared__ int lcnt[1024];
    __shared__ int lbase[1024];
    int t = threadIdx.x;
    int rep = blockIdx.x & (NREP - 1);
    int e0 = blockIdx.x << SCHUNK_SH;
    int e1 = min(e0 + SCHUNK, E);
    for (int i = t; i < NB; i += 256) lcnt[i] = 0;
    __syncthreads();
    for (int e = e0 + t; e < e1; e += 256)
        atomicAdd(&lcnt[dst[e] >> BSH], 1);
    __syncthreads();
    for (int i = t; i < NB; i += 256) {
        int c = lcnt[i];
        lbase[i] = c ? atomicAdd(&bcur8[(i << 3) | rep], c) : 0;
        lcnt[i] = 0;
    }
    __syncthreads();
    for (int e = e0 + t; e < e1; e += 256) {
        int s = src[e], d = dst[e];
        int b = d >> BSH, dl = d & (BNODES - 1);
        int pos = lbase[b] + atomicAdd(&lcnt[b], 1);
        staged[pos] = (unsigned int)s | ((unsigned int)dl << 25);
    }
}

// ---- k4: per-bucket finalize: row_ptr, dinv, csr_src + degree histogram ----
__global__ __launch_bounds__(256) void bucket_place_kernel(
        const unsigned int* __restrict__ staged, const int* __restrict__ bbase,
        int* __restrict__ row_ptr, float* __restrict__ dinv,
        int* __restrict__ csr_src, int* __restrict__ dhist8, int N, int E) {
    int b = blockIdx.x;
    int t = threadIdx.x;
    int base = bbase[b], end = bbase[b + 1];
    __shared__ int cnt[BNODES];
    __shared__ int cur[BNODES];
    __shared__ int dh[256];
    __shared__ int wsum2[2];
    if (t < BNODES) cnt[t] = 0;
    dh[t] = 0;
    __syncthreads();
    for (int i = base + t; i < end; i += 256)
        atomicAdd(&cnt[staged[i] >> 25], 1);
    __syncthreads();

    bool act = t < BNODES;
    int v = act ? cnt[t] : 0;
    int lane = t & 63, wv = t >> 6;
    int x = v;
    #pragma unroll
    for (int o = 1; o < 64; o <<= 1) {
        int y = __shfl_up(x, o);
        if (lane >= o) x += y;
    }
    if (lane == 63 && wv == 0) wsum2[0] = x;
    __syncthreads();
    if (act) {
        int excl = x - v + (wv == 1 ? wsum2[0] : 0);
        int gnode = b * BNODES + t;
        int rp = base + excl;
        cur[t] = rp;
        if (gnode < N) {
            row_ptr[gnode] = rp;
            dinv[gnode] = rsqrtf((float)v + 1.0f);
            atomicAdd(&dh[min(v, 255)], 1);      // degree histogram (LDS)
        }
    }
    __syncthreads();
    for (int i = base + t; i < end; i += 256) {
        unsigned int u = staged[i];
        int dl = u >> 25;
        int p = atomicAdd(&cur[dl], 1);
        csr_src[p] = (int)(u & 0x1FFFFFFu);
    }
    // flush degree histogram to (degree, replica) counters
    int rr = b & 31;
    if (dh[t]) atomicAdd(&dhist8[(t << 5) | rr], dh[t]);
    if (b == 0 && t == 0) row_ptr[N] = E;
}

// ---- k5: exclusive scan of dhist8[256*32] -> dcur8 ----
__global__ __launch_bounds__(1024) void scanD_kernel(
        const int* __restrict__ dh8, int* __restrict__ dcur8) {
    int t = threadIdx.x;
    int base = t * 8;
    int v[8];
    #pragma unroll
    for (int i = 0; i < 8; ++i) v[i] = dh8[base + i];
    int local = 0;
    #pragma unroll
    for (int i = 0; i < 8; ++i) local += v[i];
    int lane = t & 63, wv = t >> 6;
    int x = local;
    #pragma unroll
    for (int o = 1; o < 64; o <<= 1) {
        int y = __shfl_up(x, o);
        if (lane >= o) x += y;
    }
    __shared__ int wsum[16];
    if (lane == 63) wsum[wv] = x;
    __syncthreads();
    int woff = 0;
    for (int i = 0; i < wv; ++i) woff += wsum[i];
    int run = woff + x - local;
    #pragma unroll
    for (int i = 0; i < 8; ++i) {
        dcur8[base + i] = run;
        run += v[i];
    }
}

// ---- k6: degree-sort placement: perm[p] = node, p from (deg,replica) cursor ----
__global__ __launch_bounds__(128) void dperm_kernel(
        const int* __restrict__ row_ptr, int* __restrict__ dcur8,
        int* __restrict__ perm, int N) {
    int b = blockIdx.x;
    int node = b * BNODES + threadIdx.x;
    if (node < N) {
        int dc = min(row_ptr[node + 1] - row_ptr[node], 255);
        int p = atomicAdd(&dcur8[(dc << 5) | (b & 31)], 1);
        perm[p] = node;
    }
}

// ---- MFMA GEMM: Hs[N][128] = bf16( (X[N][128] @ W) * dinv[row] ) ----
template <bool IN_FP32>
__global__ __launch_bounds__(256) void mfma_gemm_kernel(
        const void* __restrict__ Xv, const __hip_bfloat16* __restrict__ Wt,
        const float* __restrict__ dinv, __hip_bfloat16* __restrict__ Y, int N) {
    __shared__ short Ws[FEAT][136];
    int t = threadIdx.x;
    for (int i = t; i < FEAT * 16; i += 256) {
        int n = i >> 4, c = i & 15;
        *(uint4*)&Ws[n][c * 8] = *(const uint4*)((const unsigned short*)Wt + n * FEAT + c * 8);
    }
    __syncthreads();

    int wave = t >> 6, lane = t & 63;
    int m = lane & 15, quad = lane >> 4;
    int rbase = (blockIdx.x * 4 + wave) * 16;
    if (rbase >= N) return;                 // wave-uniform
    int row = rbase + m;
    bool rok = row < N;

    f32x4 acc[8];
    #pragma unroll
    for (int nt = 0; nt < 8; ++nt) acc[nt] = (f32x4){0.f, 0.f, 0.f, 0.f};

    #pragma unroll
    for (int ks = 0; ks < 4; ++ks) {
        short8 a;
        if (IN_FP32) {
            const float* X = (const float*)Xv;
            float xs[8];
            if (rok) {
                float4 x0 = *(const float4*)(X + (size_t)row * FEAT + ks * 32 + quad * 8);
                float4 x1 = *(const float4*)(X + (size_t)row * FEAT + ks * 32 + quad * 8 + 4);
                xs[0] = x0.x; xs[1] = x0.y; xs[2] = x0.z; xs[3] = x0.w;
                xs[4] = x1.x; xs[5] = x1.y; xs[6] = x1.z; xs[7] = x1.w;
            } else {
                #pragma unroll
                for (int j = 0; j < 8; ++j) xs[j] = 0.f;
            }
            #pragma unroll
            for (int j = 0; j < 8; ++j) a[j] = (short)bf16_rn(xs[j]);
        } else {
            const unsigned short* X = (const unsigned short*)Xv;
            if (rok)
                a = *(const short8*)(X + (size_t)row * FEAT + ks * 32 + quad * 8);
            else {
                #pragma unroll
                for (int j = 0; j < 8; ++j) a[j] = 0;
            }
        }
        #pragma unroll
        for (int nt = 0; nt < 8; ++nt) {
            short8 bfr = *(const short8*)&Ws[nt * 16 + m][ks * 32 + quad * 8];
            acc[nt] = __builtin_amdgcn_mfma_f32_16x16x32_bf16(a, bfr, acc[nt], 0, 0, 0);
        }
    }

    float dr[4];
    #pragma unroll
    for (int r = 0; r < 4; ++r) {
        int ro = rbase + quad * 4 + r;
        dr[r] = (ro < N) ? dinv[ro] : 0.f;
    }
    unsigned short* Yo = (unsigned short*)Y;
    #pragma unroll
    for (int nt = 0; nt < 8; ++nt) {
        #pragma unroll
        for (int r = 0; r < 4; ++r) {
            int ro = rbase + quad * 4 + r;
            if (ro < N)
                Yo[(size_t)ro * FEAT + nt * 16 + m] = bf16_rn(acc[nt][r] * dr[r]);
        }
    }
}

// ---- fused CSR gather + MFMA epilogue, degree-uniform blocks ----
// Identical to R17 except node = perm[slot]: blocks process 16 nodes of
// ~equal degree, collapsing wave divergence (max-of-4) and the barrier
// straggler (max-of-16). Epilogue resolves rows through perm.
template <int EPI>
__global__ __launch_bounds__(256, 4) void gather_fused_kernel(
        const int* __restrict__ row_ptr, const int* __restrict__ csr_src,
        const float* __restrict__ dinv, const __hip_bfloat16* __restrict__ Hs,
        const float* __restrict__ bias, const __hip_bfloat16* __restrict__ Wt,
        const float* __restrict__ bvec, const int* __restrict__ perm,
        void* __restrict__ outp, int N) {
    __shared__ short As[16][136];

    int t = threadIdx.x;
    int lane = t & 63;
    int wave = t >> 6;
    int grp = lane >> 4;                 // node group within wave, 0..3
    int fl = lane & 15;                  // uint4 index within 256B row
    int po = blockIdx.x * 16 + wave * 4 + grp;
    bool nok = po < N;
    int nd = nok ? perm[po] : 0;         // degree-sorted node; write masked

    const char* Hb = (const char*)Hs;
    unsigned foff = (unsigned)fl << 4;

    // hoisted: self row, dinv, bias — in flight under the whole edge loop
    uint4 hu = *(const uint4*)(Hb + (((unsigned)nd << 8) + foff));
    float di = dinv[nd];
    float4 b0 = ((const float4*)bias)[fl * 2];
    float4 b1 = ((const float4*)bias)[fl * 2 + 1];

    float acc[8];
    #pragma unroll
    for (int i = 0; i < 8; ++i) acc[i] = 0.f;

    int j = row_ptr[nd], end = row_ptr[nd + 1];

    // main: GDEPTH rows per batch per group, 4*GDEPTH rows in flight per wave
    for (; j + GDEPTH <= end; j += GDEPTH) {
        unsigned off[GDEPTH];
        #pragma unroll
        for (int k = 0; k < GDEPTH; ++k)
            off[k] = ((unsigned)csr_src[j + k] << 8) + foff;
        uint4 u[GDEPTH];
        #pragma unroll
        for (int k = 0; k < GDEPTH; ++k)
            u[k] = *(const uint4*)(Hb + off[k]);
        #pragma unroll
        for (int k = 0; k < GDEPTH; ++k) {
            acc[0] += bf16_lo(u[k].x); acc[1] += bf16_hi(u[k].x);
            acc[2] += bf16_lo(u[k].y); acc[3] += bf16_hi(u[k].y);
            acc[4] += bf16_lo(u[k].z); acc[5] += bf16_hi(u[k].z);
            acc[6] += bf16_lo(u[k].w); acc[7] += bf16_hi(u[k].w);
        }
    }
    // tail: one predicated batch (loads clamped to first valid edge, adds gated)
    if (j < end) {
        int mm = end - j;                // 1..GDEPTH-1
        unsigned off[GDEPTH];
        #pragma unroll
        for (int k = 0; k < GDEPTH; ++k)
            off[k] = ((unsigned)csr_src[j + (k < mm ? k : 0)] << 8) + foff;
        uint4 u[GDEPTH];
        #pragma unroll
        for (int k = 0; k < GDEPTH; ++k)
            u[k] = *(const uint4*)(Hb + off[k]);
        #pragma unroll
        for (int k = 0; k < GDEPTH; ++k) {
            if (k < mm) {
                acc[0] += bf16_lo(u[k].x); acc[1] += bf16_hi(u[k].x);
                acc[2] += bf16_lo(u[k].y); acc[3] += bf16_hi(u[k].y);
                acc[4] += bf16_lo(u[k].z); acc[5] += bf16_hi(u[k].z);
                acc[6] += bf16_lo(u[k].w); acc[7] += bf16_hi(u[k].w);
            }
        }
    }

    // self-loop row
    acc[0] += bf16_lo(hu.x); acc[1] += bf16_hi(hu.x);
    acc[2] += bf16_lo(hu.y); acc[3] += bf16_hi(hu.y);
    acc[4] += bf16_lo(hu.z); acc[5] += bf16_hi(hu.z);
    acc[6] += bf16_lo(hu.w); acc[7] += bf16_hi(hu.w);

    float v0 = fmaxf(di * acc[0] + b0.x, 0.f);
    float v1 = fmaxf(di * acc[1] + b0.y, 0.f);
    float v2 = fmaxf(di * acc[2] + b0.z, 0.f);
    float v3 = fmaxf(di * acc[3] + b0.w, 0.f);
    float v4 = fmaxf(di * acc[4] + b1.x, 0.f);
    float v5 = fmaxf(di * acc[5] + b1.y, 0.f);
    float v6 = fmaxf(di * acc[6] + b1.z, 0.f);
    float v7 = fmaxf(di * acc[7] + b1.w, 0.f);

    uint4 o;
    o.x = (unsigned int)bf16_rn(v0) | ((unsigned int)bf16_rn(v1) << 16);
    o.y = (unsigned int)bf16_rn(v2) | ((unsigned int)bf16_rn(v3) << 16);
    o.z = (unsigned int)bf16_rn(v4) | ((unsigned int)bf16_rn(v5) << 16);
    o.w = (unsigned int)bf16_rn(v6) | ((unsigned int)bf16_rn(v7) << 16);

    // hand off this wave's 4 rows to the block A-tile (garbage rows masked
    // later: MFMA D-row m depends only on A-row m)
    *(uint4*)&As[wave * 4 + grp][fl * 8] = o;

    int m = lane & 15, quad = lane >> 4;
    int rbase0 = blockIdx.x * 16;
    const unsigned short* Wu = (const unsigned short*)Wt;

    if (EPI == 1) {
        // prefetch this lane's B-fragments + perm rows + dinv BEFORE the
        // barrier: loads fly during the straggler wait.
        short8 bf[2][4];
        #pragma unroll
        for (int n2 = 0; n2 < 2; ++n2)
            #pragma unroll
            for (int ks = 0; ks < 4; ++ks)
                bf[n2][ks] = *(const short8*)(
                    Wu + ((wave * 2 + n2) * 16 + m) * FEAT + ks * 32 + quad * 8);
        int ror[4];
        float dr[4];
        #pragma unroll
        for (int r = 0; r < 4; ++r) {
            int p2 = rbase0 + quad * 4 + r;
            ror[r] = (p2 < N) ? perm[p2] : -1;
            dr[r] = (ror[r] >= 0) ? dinv[ror[r]] : 0.f;
        }
        __syncthreads();
        f32x4 acc2[2];
        #pragma unroll
        for (int n2 = 0; n2 < 2; ++n2) acc2[n2] = (f32x4){0.f, 0.f, 0.f, 0.f};
        #pragma unroll
        for (int ks = 0; ks < 4; ++ks) {
            short8 a = *(const short8*)&As[m][ks * 32 + quad * 8];
            #pragma unroll
            for (int n2 = 0; n2 < 2; ++n2)
                acc2[n2] = __builtin_amdgcn_mfma_f32_16x16x32_bf16(a, bf[n2][ks], acc2[n2], 0, 0, 0);
        }
        unsigned short* Yo = (unsigned short*)outp;
        #pragma unroll
        for (int r = 0; r < 4; ++r) {
            if (ror[r] >= 0) {
                #pragma unroll
                for (int n2 = 0; n2 < 2; ++n2)
                    Yo[(size_t)ror[r] * FEAT + (wave * 2 + n2) * 16 + m] =
                        bf16_rn(acc2[n2][r] * dr[r]);
            }
        }
    } else {
        // wave 0 prefetches its 16 B-fragments + bias + perm rows pre-barrier
        short8 bf[4][4];
        float bj[4];
        int ror[4];
        if (wave == 0) {
            #pragma unroll
            for (int nt = 0; nt < 4; ++nt)
                #pragma unroll
                for (int ks = 0; ks < 4; ++ks)
                    bf[nt][ks] = *(const short8*)(
                        Wu + (nt * 16 + m) * FEAT + ks * 32 + quad * 8);
            #pragma unroll
            for (int nt = 0; nt < 4; ++nt) bj[nt] = bvec[nt * 16 + m];
            #pragma unroll
            for (int r = 0; r < 4; ++r) {
                int p2 = rbase0 + quad * 4 + r;
                ror[r] = (p2 < N) ? perm[p2] : -1;
            }
        }
        __syncthreads();
        if (wave == 0) {
            f32x4 acc4[4];
            #pragma unroll
            for (int nt = 0; nt < 4; ++nt) acc4[nt] = (f32x4){0.f, 0.f, 0.f, 0.f};
            #pragma unroll
            for (int ks = 0; ks < 4; ++ks) {
                short8 a = *(const short8*)&As[m][ks * 32 + quad * 8];
                #pragma unroll
                for (int nt = 0; nt < 4; ++nt)
                    acc4[nt] = __builtin_amdgcn_mfma_f32_16x16x32_bf16(a, bf[nt][ks], acc4[nt], 0, 0, 0);
            }
            float* out = (float*)outp;
            #pragma unroll
            for (int r = 0; r < 4; ++r) {
                if (ror[r] < 0) continue;        // uniform within 16-lane group
                float w0 = acc4[0][r] + bj[0];
                float w1 = acc4[1][r] + bj[1];
                float w2 = acc4[2][r] + bj[2];
                float w3 = acc4[3][r] + bj[3];
                float mx = fmaxf(fmaxf(w0, w1), fmaxf(w2, w3));
                #pragma unroll
                for (int os = 1; os <= 8; os <<= 1) mx = fmaxf(mx, __shfl_xor(mx, os));
                float s = __expf(w0 - mx) + __expf(w1 - mx) + __expf(w2 - mx) + __expf(w3 - mx);
                #pragma unroll
                for (int os = 1; os <= 8; os <<= 1) s += __shfl_xor(s, os);
                float ls = mx + __logf(s);
                float* op = out + (size_t)ror[r] * OUTF + m;
                op[0]  = w0 - ls;
                op[16] = w1 - ls;
                op[32] = w2 - ls;
                op[48] = w3 - ls;
            }
        }
    }
}

extern "C" void kernel_launch(void* const* d_in, const int* in_sizes, int n_in,
                              void* d_out, int out_size, void* d_ws, size_t ws_size,
                              hipStream_t stream) {
    const float* x    = (const float*)d_in[0];
    const int*   ei   = (const int*)  d_in[1];
    const float* W1   = (const float*)d_in[2];
    const float* b1   = (const float*)d_in[3];
    const float* W2   = (const float*)d_in[4];
    const float* b2   = (const float*)d_in[5];
    const float* Wout = (const float*)d_in[6];
    const float* bout = (const float*)d_in[7];
    float* out = (float*)d_out;

    int N = in_sizes[0] / FEAT;
    int E = in_sizes[1] / 2;
    const int* srcp = ei;
    const int* dstp = ei + E;
    int NB = (N + BNODES - 1) >> BSH;   // <= 1024 for N <= 131072

    char* ws = (char*)d_ws;
    __hip_bfloat16* Bh   = (__hip_bfloat16*)ws;                   // N*128 bf16
    __hip_bfloat16* Ba   = Bh + (size_t)N * FEAT;                 // N*128 bf16
    __hip_bfloat16* W1t  = Ba + (size_t)N * FEAT;                 // 16384 bf16
    __hip_bfloat16* W2t  = W1t + FEAT * FEAT;                     // 16384 bf16
    __hip_bfloat16* WoutT = W2t + FEAT * FEAT;                    // 8192 bf16
    float* dinv    = (float*)(WoutT + OUTF * FEAT);               // N
    int*   rowp    = (int*)(dinv + N);                            // N+1
    int*   bcnt8   = rowp + N + 1;                                // 8192
    int*   bcur8   = bcnt8 + 8192;                                // 8192
    int*   bbase   = bcur8 + 8192;                                // NB+1 (pad 1032)
    int*   dhist8  = bbase + 1032;                                // 8192
    int*   dcur8   = dhist8 + 8192;                               // 8192
    int*   perm    = dcur8 + 8192;                                // N
    unsigned int* staged = (unsigned int*)(perm + N);             // E
    int*   csrsrc  = (int*)(staged + E);                          // E

    // k0: convert weights + zero bcnt8/dhist8 (replaces memset)
    convw_kernel<<<224, 256, 0, stream>>>(
        W1, W2, Wout, W1t, W2t, WoutT, bcnt8, dhist8);
    bincount8_kernel<<<256, 256, 0, stream>>>(dstp, bcnt8, E, NB);
    bucket_scan8_kernel<<<1, 1024, 0, stream>>>(bcnt8, bcur8, bbase, NB, E);
    bin_scatter_kernel<<<(E + SCHUNK - 1) / SCHUNK, 256, 0, stream>>>(
        srcp, dstp, bcur8, staged, E, NB);
    bucket_place_kernel<<<NB, 256, 0, stream>>>(
        staged, bbase, rowp, dinv, csrsrc, dhist8, N, E);
    scanD_kernel<<<1, 1024, 0, stream>>>(dhist8, dcur8);
    dperm_kernel<<<NB, 128, 0, stream>>>(rowp, dcur8, perm, N);

    int ggrid = (N + 63) / 64;
    int agrid = (N + 15) / 16;

    // Layer 1 GEMM: Bh = (x @ W1) * dinv   (bf16, prescaled)
    mfma_gemm_kernel<true><<<ggrid, 256, 0, stream>>>(x, W1t, dinv, Bh, N);

    // Layer 1 gather + Layer 2 GEMM fused: Ba = ((relu(gather(Bh))+b1) @ W2) * dinv
    gather_fused_kernel<1><<<agrid, 256, 0, stream>>>(
        rowp, csrsrc, dinv, Bh, b1, W2t, nullptr, perm, Ba, N);

    // Layer 2 gather + output layer + log_softmax fused
    gather_fused_kernel<2><<<agrid, 256, 0, stream>>>(
        rowp, csrsrc, dinv, Ba, b2, WoutT, bout, perm, out, N);
}

// Round 10
// 338.291 us; speedup vs baseline: 1.2542x; 1.2542x over previous
//
#include <hip/hip_runtime.h>
#include <hip/hip_bf16.h>

// 3-layer GCN. Round 19: R17 core (best, 316.7us; fused gathers byte-
// identical) + preprocessing coalescing fixes targeting the ~177us
// non-gather remainder:
//  - SCHUNK 4096->16384: bin_scatter blocks write ~16-consecutive staged
//    entries per bucket range (64B runs) instead of ~4 (16B) -> kills the
//    4-8x scattered-write amplification.
//  - bincount8 grid 256->64: LDS histogram flush drops 1.2M->0.5M global
//    atomics; 6.4MB edge read still streams.
//  - memset folded into convw (zero-fill blocks); one dispatch fewer.
// R18 lesson: degree-sort dperm = 93us of serialized hot-bin atomics, and
// perm indirection negates the skew gain — reverted entirely.
//   convw(+zero) -> bincount8 -> bucket_scan8 -> bin_scatter ->
//   bucket_place -> gemm1 -> fused1 -> fused2
// Requires N <= 131072 (NB <= 1024) and N < 2^25 for packing.

#define FEAT 128
#define OUTF 64
#define BSH 7                 // 128 nodes per bucket
#define BNODES (1 << BSH)
#define SCHUNK_SH 14          // 16384 edges per bin_scatter block
#define SCHUNK (1 << SCHUNK_SH)
#define NREP 8                // cursor replicas per bucket
#define GDEPTH 16             // gather unroll depth (rows in flight per group)

typedef __attribute__((ext_vector_type(8))) short short8;
typedef __attribute__((ext_vector_type(4))) float f32x4;

__device__ __forceinline__ unsigned short bf16_rn(float f) {
    unsigned int u = __float_as_uint(f);
    u += 0x7FFFu + ((u >> 16) & 1u);   // round-to-nearest-even
    return (unsigned short)(u >> 16);
}
__device__ __forceinline__ float bf16_lo(unsigned int u) { return __uint_as_float(u << 16); }
__device__ __forceinline__ float bf16_hi(unsigned int u) { return __uint_as_float(u & 0xFFFF0000u); }

// ---- k0: weight convert + zero bcnt8 (replaces memset dispatch) ----
// blocks 0..159: conv; 160..191: zero bcnt8 (32 x 256 = 8192).
__global__ __launch_bounds__(256) void convw_kernel(
        const float* __restrict__ W1, const float* __restrict__ W2,
        const float* __restrict__ Wout,
        __hip_bfloat16* __restrict__ W1t, __hip_bfloat16* __restrict__ W2t,
        __hip_bfloat16* __restrict__ WoutT, int* __restrict__ bcnt8) {
    int bx = blockIdx.x;
    if (bx >= 160) {
        bcnt8[((bx & 31) << 8) | threadIdx.x] = 0;
        return;
    }
    int idx = bx * 256 + threadIdx.x;
    if (idx < 2 * FEAT * FEAT) {
        int which = idx >> 14;               // /16384
        int r = idx & (FEAT * FEAT - 1);
        int n = r >> 7, k = r & 127;
        const float* W = which ? W2 : W1;
        unsigned short* Wt = (unsigned short*)(which ? W2t : W1t);
        Wt[r] = bf16_rn(W[k * FEAT + n]);
    } else if (idx < 2 * FEAT * FEAT + OUTF * FEAT) {
        int r = idx - 2 * FEAT * FEAT;
        int n = r >> 7, k = r & 127;         // n<64 out-col, k<128 hidden
        ((unsigned short*)WoutT)[r] = bf16_rn(Wout[k * OUTF + n]);
    }
}

// ---- k1: per-(bucket,replica) edge counts; replica = chunk&7 ----
// 64 blocks: histogram fills (~25K edges over 8K counters) before flush,
// so the global flush is ~0.5M atomics instead of ~1.2M.
__global__ __launch_bounds__(256) void bincount8_kernel(
        const int* __restrict__ dst, int* __restrict__ bcnt8, int E, int NB) {
    __shared__ int h[8192];
    int t = threadIdx.x;
    int nb8 = NB * NREP;
    for (int i = t; i < nb8; i += 256) h[i] = 0;
    __syncthreads();
    int stride = gridDim.x * 256;
    for (int e = blockIdx.x * 256 + t; e < E; e += stride) {
        int rep = (e >> SCHUNK_SH) & (NREP - 1);
        atomicAdd(&h[((dst[e] >> BSH) << 3) | rep], 1);
    }
    __syncthreads();
    for (int i = t; i < nb8; i += 256)
        if (h[i]) atomicAdd(&bcnt8[i], h[i]);
}

// ---- k2: exclusive scan of bcnt8[NB*8] -> bcur8 (absolute positions), bbase ----
__global__ __launch_bounds__(1024) void bucket_scan8_kernel(
        const int* __restrict__ bcnt8, int* __restrict__ bcur8,
        int* __restrict__ bbase, int NB, int E) {
    int t = threadIdx.x;
    int nb8 = NB * NREP;
    int base = t * 8;
    int v[8];
    #pragma unroll
    for (int i = 0; i < 8; ++i) v[i] = (base + i < nb8) ? bcnt8[base + i] : 0;
    int local = 0;
    #pragma unroll
    for (int i = 0; i < 8; ++i) local += v[i];
    int lane = t & 63, wv = t >> 6;
    int x = local;
    #pragma unroll
    for (int o = 1; o < 64; o <<= 1) {
        int y = __shfl_up(x, o);
        if (lane >= o) x += y;
    }
    __shared__ int wsum[16];
    if (lane == 63) wsum[wv] = x;
    __syncthreads();
    int woff = 0;
    for (int i = 0; i < wv; ++i) woff += wsum[i];
    int run = woff + x - local;
    #pragma unroll
    for (int i = 0; i < 8; ++i) {
        int g = base + i;
        if (g < nb8) {
            bcur8[g] = run;
            if ((g & (NREP - 1)) == 0) bbase[g >> 3] = run;
        }
        run += v[i];
    }
    if (t == 0) bbase[NB] = E;
}

// ---- k3: two-phase scatter of packed (src | dlocal<<25), bucket-major ----
// 16384-edge chunks: ~16 consecutive staged entries per bucket range per
// block -> 64B contiguous write runs (was ~4 entries / 16B at SCHUNK=4096).
__global__ __launch_bounds__(256) void bin_scatter_kernel(
        const int* __restrict__ src, const int* __restrict__ dst,
        int* __restrict__ bcur8, unsigned int* __restrict__ staged,
        int E, int NB) {
    __shared__ int lcnt[1024];
    __shared__ int lbase[1024];
    int t = threadIdx.x;
    int rep = blockIdx.x & (NREP - 1);
    int e0 = blockIdx.x << SCHUNK_SH;
    int e1 = min(e0 + SCHUNK, E);
    for (int i = t; i < NB; i += 256) lcnt[i] = 0;
    __syncthreads();
    for (int e = e0 + t; e < e1; e += 256)
        atomicAdd(&lcnt[dst[e] >> BSH], 1);
    __syncthreads();
    for (int i = t; i < NB; i += 256) {
        int c = lcnt[i];
        lbase[i] = c ? atomicAdd(&bcur8[(i << 3) | rep], c) : 0;
        lcnt[i] = 0;
    }
    __syncthreads();
    for (int e = e0 + t; e < e1; e += 256) {
        int s = src[e], d = dst[e];
        int b = d >> BSH, dl = d & (BNODES - 1);
        int pos = lbase[b] + atomicAdd(&lcnt[b], 1);
        staged[pos] = (unsigned int)s | ((unsigned int)dl << 25);
    }
}

// ---- k4: per-bucket finalize: row_ptr, dinv, csr_src ----
__global__ __launch_bounds__(256) void bucket_place_kernel(
        const unsigned int* __restrict__ staged, const int* __restrict__ bbase,
        int* __restrict__ row_ptr, float* __restrict__ dinv,
        int* __restrict__ csr_src, int N, int E) {
    int b = blockIdx.x;
    int t = threadIdx.x;
    int base = bbase[b], end = bbase[b + 1];
    __shared__ int cnt[BNODES];
    __shared__ int cur[BNODES];
    __shared__ int wsum2[2];
    if (t < BNODES) cnt[t] = 0;
    __syncthreads();
    for (int i = base + t; i < end; i += 256)
        atomicAdd(&cnt[staged[i] >> 25], 1);
    __syncthreads();

    bool act = t < BNODES;
    int v = act ? cnt[t] : 0;
    int lane = t & 63, wv = t >> 6;
    int x = v;
    #pragma unroll
    for (int o = 1; o < 64; o <<= 1) {
        int y = __shfl_up(x, o);
        if (lane >= o) x += y;
    }
    if (lane == 63 && wv == 0) wsum2[0] = x;
    __syncthreads();
    if (act) {
        int excl = x - v + (wv == 1 ? wsum2[0] : 0);
        int gnode = b * BNODES + t;
        int rp = base + excl;
        cur[t] = rp;
        if (gnode < N) {
            row_ptr[gnode] = rp;
            dinv[gnode] = rsqrtf((float)v + 1.0f);
        }
    }
    __syncthreads();
    for (int i = base + t; i < end; i += 256) {
        unsigned int u = staged[i];
        int dl = u >> 25;
        int p = atomicAdd(&cur[dl], 1);
        csr_src[p] = (int)(u & 0x1FFFFFFu);
    }
    if (b == 0 && t == 0) row_ptr[N] = E;
}

// ---- MFMA GEMM: Hs[N][128] = bf16( (X[N][128] @ W) * dinv[row] ) ----
template <bool IN_FP32>
__global__ __launch_bounds__(256) void mfma_gemm_kernel(
        const void* __restrict__ Xv, const __hip_bfloat16* __restrict__ Wt,
        const float* __restrict__ dinv, __hip_bfloat16* __restrict__ Y, int N) {
    __shared__ short Ws[FEAT][136];
    int t = threadIdx.x;
    for (int i = t; i < FEAT * 16; i += 256) {
        int n = i >> 4, c = i & 15;
        *(uint4*)&Ws[n][c * 8] = *(const uint4*)((const unsigned short*)Wt + n * FEAT + c * 8);
    }
    __syncthreads();

    int wave = t >> 6, lane = t & 63;
    int m = lane & 15, quad = lane >> 4;
    int rbase = (blockIdx.x * 4 + wave) * 16;
    if (rbase >= N) return;                 // wave-uniform
    int row = rbase + m;
    bool rok = row < N;

    f32x4 acc[8];
    #pragma unroll
    for (int nt = 0; nt < 8; ++nt) acc[nt] = (f32x4){0.f, 0.f, 0.f, 0.f};

    #pragma unroll
    for (int ks = 0; ks < 4; ++ks) {
        short8 a;
        if (IN_FP32) {
            const float* X = (const float*)Xv;
            float xs[8];
            if (rok) {
                float4 x0 = *(const float4*)(X + (size_t)row * FEAT + ks * 32 + quad * 8);
                float4 x1 = *(const float4*)(X + (size_t)row * FEAT + ks * 32 + quad * 8 + 4);
                xs[0] = x0.x; xs[1] = x0.y; xs[2] = x0.z; xs[3] = x0.w;
                xs[4] = x1.x; xs[5] = x1.y; xs[6] = x1.z; xs[7] = x1.w;
            } else {
                #pragma unroll
                for (int j = 0; j < 8; ++j) xs[j] = 0.f;
            }
            #pragma unroll
            for (int j = 0; j < 8; ++j) a[j] = (short)bf16_rn(xs[j]);
        } else {
            const unsigned short* X = (const unsigned short*)Xv;
            if (rok)
                a = *(const short8*)(X + (size_t)row * FEAT + ks * 32 + quad * 8);
            else {
                #pragma unroll
                for (int j = 0; j < 8; ++j) a[j] = 0;
            }
        }
        #pragma unroll
        for (int nt = 0; nt < 8; ++nt) {
            short8 bfr = *(const short8*)&Ws[nt * 16 + m][ks * 32 + quad * 8];
            acc[nt] = __builtin_amdgcn_mfma_f32_16x16x32_bf16(a, bfr, acc[nt], 0, 0, 0);
        }
    }

    float dr[4];
    #pragma unroll
    for (int r = 0; r < 4; ++r) {
        int ro = rbase + quad * 4 + r;
        dr[r] = (ro < N) ? dinv[ro] : 0.f;
    }
    unsigned short* Yo = (unsigned short*)Y;
    #pragma unroll
    for (int nt = 0; nt < 8; ++nt) {
        #pragma unroll
        for (int r = 0; r < 4; ++r) {
            int ro = rbase + quad * 4 + r;
            if (ro < N)
                Yo[(size_t)ro * FEAT + nt * 16 + m] = bf16_rn(acc[nt][r] * dr[r]);
        }
    }
}

// ---- fused CSR gather + MFMA epilogue (R17, byte-identical) ----
// Gather: 4 nodes/wave, 16 lanes x uint4/row, GDEPTH-deep. Block = 16
// nodes = one MFMA M-tile; rows land in LDS As[16][136]. B-fragments
// register-prefetched between As-write and barrier (straggler wait hides
// their latency).
//   EPI==1: 4 waves x 2 N-tiles of As@W2, scale by dinv, write bf16.
//   EPI==2: wave 0: As@Wout + bout, log_softmax, fp32 out.
template <int EPI>
__global__ __launch_bounds__(256, 4) void gather_fused_kernel(
        const int* __restrict__ row_ptr, const int* __restrict__ csr_src,
        const float* __restrict__ dinv, const __hip_bfloat16* __restrict__ Hs,
        const float* __restrict__ bias, const __hip_bfloat16* __restrict__ Wt,
        const float* __restrict__ bvec, void* __restrict__ outp, int N) {
    __shared__ short As[16][136];

    int t = threadIdx.x;
    int lane = t & 63;
    int wave = t >> 6;
    int grp = lane >> 4;                 // node group within wave, 0..3
    int fl = lane & 15;                  // uint4 index within 256B row
    int node = blockIdx.x * 16 + wave * 4 + grp;
    bool nok = node < N;
    int nd = nok ? node : 0;             // clamp for safe loads; write masked

    const char* Hb = (const char*)Hs;
    unsigned foff = (unsigned)fl << 4;

    // hoisted: self row, dinv, bias — in flight under the whole edge loop
    uint4 hu = *(const uint4*)(Hb + (((unsigned)nd << 8) + foff));
    float di = dinv[nd];
    float4 b0 = ((const float4*)bias)[fl * 2];
    float4 b1 = ((const float4*)bias)[fl * 2 + 1];

    float acc[8];
    #pragma unroll
    for (int i = 0; i < 8; ++i) acc[i] = 0.f;

    int j = row_ptr[nd], end = row_ptr[nd + 1];

    // main: GDEPTH rows per batch per group, 4*GDEPTH rows in flight per wave
    for (; j + GDEPTH <= end; j += GDEPTH) {
        unsigned off[GDEPTH];
        #pragma unroll
        for (int k = 0; k < GDEPTH; ++k)
            off[k] = ((unsigned)csr_src[j + k] << 8) + foff;
        uint4 u[GDEPTH];
        #pragma unroll
        for (int k = 0; k < GDEPTH; ++k)
            u[k] = *(const uint4*)(Hb + off[k]);
        #pragma unroll
        for (int k = 0; k < GDEPTH; ++k) {
            acc[0] += bf16_lo(u[k].x); acc[1] += bf16_hi(u[k].x);
            acc[2] += bf16_lo(u[k].y); acc[3] += bf16_hi(u[k].y);
            acc[4] += bf16_lo(u[k].z); acc[5] += bf16_hi(u[k].z);
            acc[6] += bf16_lo(u[k].w); acc[7] += bf16_hi(u[k].w);
        }
    }
    // tail: one predicated batch (loads clamped to first valid edge, adds gated)
    if (j < end) {
        int mm = end - j;                // 1..GDEPTH-1
        unsigned off[GDEPTH];
        #pragma unroll
        for (int k = 0; k < GDEPTH; ++k)
            off[k] = ((unsigned)csr_src[j + (k < mm ? k : 0)] << 8) + foff;
        uint4 u[GDEPTH];
        #pragma unroll
        for (int k = 0; k < GDEPTH; ++k)
            u[k] = *(const uint4*)(Hb + off[k]);
        #pragma unroll
        for (int k = 0; k < GDEPTH; ++k) {
            if (k < mm) {
                acc[0] += bf16_lo(u[k].x); acc[1] += bf16_hi(u[k].x);
                acc[2] += bf16_lo(u[k].y); acc[3] += bf16_hi(u[k].y);
                acc[4] += bf16_lo(u[k].z); acc[5] += bf16_hi(u[k].z);
                acc[6] += bf16_lo(u[k].w); acc[7] += bf16_hi(u[k].w);
            }
        }
    }

    // self-loop row
    acc[0] += bf16_lo(hu.x); acc[1] += bf16_hi(hu.x);
    acc[2] += bf16_lo(hu.y); acc[3] += bf16_hi(hu.y);
    acc[4] += bf16_lo(hu.z); acc[5] += bf16_hi(hu.z);
    acc[6] += bf16_lo(hu.w); acc[7] += bf16_hi(hu.w);

    float v0 = fmaxf(di * acc[0] + b0.x, 0.f);
    float v1 = fmaxf(di * acc[1] + b0.y, 0.f);
    float v2 = fmaxf(di * acc[2] + b0.z, 0.f);
    float v3 = fmaxf(di * acc[3] + b0.w, 0.f);
    float v4 = fmaxf(di * acc[4] + b1.x, 0.f);
    float v5 = fmaxf(di * acc[5] + b1.y, 0.f);
    float v6 = fmaxf(di * acc[6] + b1.z, 0.f);
    float v7 = fmaxf(di * acc[7] + b1.w, 0.f);

    uint4 o;
    o.x = (unsigned int)bf16_rn(v0) | ((unsigned int)bf16_rn(v1) << 16);
    o.y = (unsigned int)bf16_rn(v2) | ((unsigned int)bf16_rn(v3) << 16);
    o.z = (unsigned int)bf16_rn(v4) | ((unsigned int)bf16_rn(v5) << 16);
    o.w = (unsigned int)bf16_rn(v6) | ((unsigned int)bf16_rn(v7) << 16);

    // hand off this wave's 4 rows to the block A-tile (garbage rows masked
    // later: MFMA D-row m depends only on A-row m)
    *(uint4*)&As[wave * 4 + grp][fl * 8] = o;

    int m = lane & 15, quad = lane >> 4;
    int rbase0 = blockIdx.x * 16;
    const unsigned short* Wu = (const unsigned short*)Wt;

    if (EPI == 1) {
        // prefetch this lane's B-fragments + dinv BEFORE the barrier:
        // loads fly during the straggler wait, consumed from regs after.
        short8 bf[2][4];
        #pragma unroll
        for (int n2 = 0; n2 < 2; ++n2)
            #pragma unroll
            for (int ks = 0; ks < 4; ++ks)
                bf[n2][ks] = *(const short8*)(
                    Wu + ((wave * 2 + n2) * 16 + m) * FEAT + ks * 32 + quad * 8);
        float dr[4];
        #pragma unroll
        for (int r = 0; r < 4; ++r) {
            int ro = rbase0 + quad * 4 + r;
            dr[r] = (ro < N) ? dinv[ro] : 0.f;
        }
        __syncthreads();
        f32x4 acc2[2];
        #pragma unroll
        for (int n2 = 0; n2 < 2; ++n2) acc2[n2] = (f32x4){0.f, 0.f, 0.f, 0.f};
        #pragma unroll
        for (int ks = 0; ks < 4; ++ks) {
            short8 a = *(const short8*)&As[m][ks * 32 + quad * 8];
            #pragma unroll
            for (int n2 = 0; n2 < 2; ++n2)
                acc2[n2] = __builtin_amdgcn_mfma_f32_16x16x32_bf16(a, bf[n2][ks], acc2[n2], 0, 0, 0);
        }
        unsigned short* Yo = (unsigned short*)outp;
        #pragma unroll
        for (int r = 0; r < 4; ++r) {
            int ro = rbase0 + quad * 4 + r;
            if (ro < N) {
                #pragma unroll
                for (int n2 = 0; n2 < 2; ++n2)
                    Yo[(size_t)ro * FEAT + (wave * 2 + n2) * 16 + m] =
                        bf16_rn(acc2[n2][r] * dr[r]);
            }
        }
    } else {
        // wave 0 prefetches its 16 B-fragments + bias pre-barrier
        short8 bf[4][4];
        float bj[4];
        if (wave == 0) {
            #pragma unroll
            for (int nt = 0; nt < 4; ++nt)
                #pragma unroll
                for (int ks = 0; ks < 4; ++ks)
                    bf[nt][ks] = *(const short8*)(
                        Wu + (nt * 16 + m) * FEAT + ks * 32 + quad * 8);
            #pragma unroll
            for (int nt = 0; nt < 4; ++nt) bj[nt] = bvec[nt * 16 + m];
        }
        __syncthreads();
        if (wave == 0) {
            f32x4 acc4[4];
            #pragma unroll
            for (int nt = 0; nt < 4; ++nt) acc4[nt] = (f32x4){0.f, 0.f, 0.f, 0.f};
            #pragma unroll
            for (int ks = 0; ks < 4; ++ks) {
                short8 a = *(const short8*)&As[m][ks * 32 + quad * 8];
                #pragma unroll
                for (int nt = 0; nt < 4; ++nt)
                    acc4[nt] = __builtin_amdgcn_mfma_f32_16x16x32_bf16(a, bf[nt][ks], acc4[nt], 0, 0, 0);
            }
            float* out = (float*)outp;
            #pragma unroll
            for (int r = 0; r < 4; ++r) {
                int ro = rbase0 + quad * 4 + r;   // uniform within 16-lane group
                if (ro >= N) continue;
                float w0 = acc4[0][r] + bj[0];
                float w1 = acc4[1][r] + bj[1];
                float w2 = acc4[2][r] + bj[2];
                float w3 = acc4[3][r] + bj[3];
                float mx = fmaxf(fmaxf(w0, w1), fmaxf(w2, w3));
                #pragma unroll
                for (int os = 1; os <= 8; os <<= 1) mx = fmaxf(mx, __shfl_xor(mx, os));
                float s = __expf(w0 - mx) + __expf(w1 - mx) + __expf(w2 - mx) + __expf(w3 - mx);
                #pragma unroll
                for (int os = 1; os <= 8; os <<= 1) s += __shfl_xor(s, os);
                float ls = mx + __logf(s);
                float* op = out + (size_t)ro * OUTF + m;
                op[0]  = w0 - ls;
                op[16] = w1 - ls;
                op[32] = w2 - ls;
                op[48] = w3 - ls;
            }
        }
    }
}

extern "C" void kernel_launch(void* const* d_in, const int* in_sizes, int n_in,
                              void* d_out, int out_size, void* d_ws, size_t ws_size,
                              hipStream_t stream) {
    const float* x    = (const float*)d_in[0];
    const int*   ei   = (const int*)  d_in[1];
    const float* W1   = (const float*)d_in[2];
    const float* b1   = (const float*)d_in[3];
    const float* W2   = (const float*)d_in[4];
    const float* b2   = (const float*)d_in[5];
    const float* Wout = (const float*)d_in[6];
    const float* bout = (const float*)d_in[7];
    float* out = (float*)d_out;

    int N = in_sizes[0] / FEAT;
    int E = in_sizes[1] / 2;
    const int* srcp = ei;
    const int* dstp = ei + E;
    int NB = (N + BNODES - 1) >> BSH;   // <= 1024 for N <= 131072

    char* ws = (char*)d_ws;
    __hip_bfloat16* Bh   = (__hip_bfloat16*)ws;                   // N*128 bf16
    __hip_bfloat16* Ba   = Bh + (size_t)N * FEAT;                 // N*128 bf16
    __hip_bfloat16* W1t  = Ba + (size_t)N * FEAT;                 // 16384 bf16
    __hip_bfloat16* W2t  = W1t + FEAT * FEAT;                     // 16384 bf16
    __hip_bfloat16* WoutT = W2t + FEAT * FEAT;                    // 8192 bf16
    float* dinv    = (float*)(WoutT + OUTF * FEAT);               // N
    int*   rowp    = (int*)(dinv + N);                            // N+1
    int*   bcnt8   = rowp + N + 1;                                // 8192
    int*   bcur8   = bcnt8 + 8192;                                // 8192
    int*   bbase   = bcur8 + 8192;                                // NB+1
    unsigned int* staged = (unsigned int*)(bbase + 1032);         // E
    int*   csrsrc  = (int*)(staged + E);                          // E

    // k0: convert weights + zero bcnt8 (replaces memset dispatch)
    convw_kernel<<<192, 256, 0, stream>>>(
        W1, W2, Wout, W1t, W2t, WoutT, bcnt8);
    bincount8_kernel<<<64, 256, 0, stream>>>(dstp, bcnt8, E, NB);
    bucket_scan8_kernel<<<1, 1024, 0, stream>>>(bcnt8, bcur8, bbase, NB, E);
    bin_scatter_kernel<<<(E + SCHUNK - 1) / SCHUNK, 256, 0, stream>>>(
        srcp, dstp, bcur8, staged, E, NB);
    bucket_place_kernel<<<NB, 256, 0, stream>>>(staged, bbase, rowp, dinv, csrsrc, N, E);

    int ggrid = (N + 63) / 64;
    int agrid = (N + 15) / 16;

    // Layer 1 GEMM: Bh = (x @ W1) * dinv   (bf16, prescaled)
    mfma_gemm_kernel<true><<<ggrid, 256, 0, stream>>>(x, W1t, dinv, Bh, N);

    // Layer 1 gather + Layer 2 GEMM fused: Ba = ((relu(gather(Bh))+b1) @ W2) * dinv
    gather_fused_kernel<1><<<agrid, 256, 0, stream>>>(
        rowp, csrsrc, dinv, Bh, b1, W2t, nullptr, Ba, N);

    // Layer 2 gather + output layer + log_softmax fused
    gather_fused_kernel<2><<<agrid, 256, 0, stream>>>(
        rowp, csrsrc, dinv, Ba, b2, WoutT, bout, out, N);
}

// Round 11
// 314.091 us; speedup vs baseline: 1.3509x; 1.0770x over previous
//
#include <hip/hip_runtime.h>
#include <hip/hip_bf16.h>

// 3-layer GCN. Round 20: revert R19's preprocessing degradations back to
// the R17-proven config (SCHUNK=4096 / 391 scatter blocks; bincount8 at
// 256 blocks). R19 lesson: bin_scatter/bincount8 are latency/atomic-bound
// with writes absorbed by L2 — shrinking the grid for "coalescing" only
// removed CUs (+21.6us). Kept from R19: memset folded into convw as 32
// zero-fill blocks (same-stream ordering; one dispatch fewer).
// Fused gathers byte-identical to R17 (best: 316.7us):
//   gather 4 nodes/wave, 16 lanes x uint4/row, GDEPTH=16; As[16][136] LDS
//   handoff; B-fragments register-prefetched pre-barrier (straggler wait
//   hides their latency).
//   fused1 = gather(L1) + gemm2(W2) -> prescaled Hs2
//   fused2 = gather(L2) + Wout MFMA + log_softmax -> out
// Requires N <= 131072 (NB <= 1024) and N < 2^25 for packing.

#define FEAT 128
#define OUTF 64
#define BSH 7                 // 128 nodes per bucket
#define BNODES (1 << BSH)
#define SCHUNK_SH 12          // 4096 edges per bin_scatter block
#define SCHUNK (1 << SCHUNK_SH)
#define NREP 8                // cursor replicas per bucket
#define GDEPTH 16             // gather unroll depth (rows in flight per group)

typedef __attribute__((ext_vector_type(8))) short short8;
typedef __attribute__((ext_vector_type(4))) float f32x4;

__device__ __forceinline__ unsigned short bf16_rn(float f) {
    unsigned int u = __float_as_uint(f);
    u += 0x7FFFu + ((u >> 16) & 1u);   // round-to-nearest-even
    return (unsigned short)(u >> 16);
}
__device__ __forceinline__ float bf16_lo(unsigned int u) { return __uint_as_float(u << 16); }
__device__ __forceinline__ float bf16_hi(unsigned int u) { return __uint_as_float(u & 0xFFFF0000u); }

// ---- k0: weight convert + zero bcnt8 (replaces memset dispatch) ----
// blocks 0..159: conv; 160..191: zero bcnt8 (32 x 256 = 8192).
__global__ __launch_bounds__(256) void convw_kernel(
        const float* __restrict__ W1, const float* __restrict__ W2,
        const float* __restrict__ Wout,
        __hip_bfloat16* __restrict__ W1t, __hip_bfloat16* __restrict__ W2t,
        __hip_bfloat16* __restrict__ WoutT, int* __restrict__ bcnt8) {
    int bx = blockIdx.x;
    if (bx >= 160) {
        bcnt8[((bx & 31) << 8) | threadIdx.x] = 0;
        return;
    }
    int idx = bx * 256 + threadIdx.x;
    if (idx < 2 * FEAT * FEAT) {
        int which = idx >> 14;               // /16384
        int r = idx & (FEAT * FEAT - 1);
        int n = r >> 7, k = r & 127;
        const float* W = which ? W2 : W1;
        unsigned short* Wt = (unsigned short*)(which ? W2t : W1t);
        Wt[r] = bf16_rn(W[k * FEAT + n]);
    } else if (idx < 2 * FEAT * FEAT + OUTF * FEAT) {
        int r = idx - 2 * FEAT * FEAT;
        int n = r >> 7, k = r & 127;         // n<64 out-col, k<128 hidden
        ((unsigned short*)WoutT)[r] = bf16_rn(Wout[k * OUTF + n]);
    }
}

// ---- k1: per-(bucket,replica) edge counts; replica = chunk&7 ----
__global__ __launch_bounds__(256) void bincount8_kernel(
        const int* __restrict__ dst, int* __restrict__ bcnt8, int E, int NB) {
    __shared__ int h[8192];
    int t = threadIdx.x;
    int nb8 = NB * NREP;
    for (int i = t; i < nb8; i += 256) h[i] = 0;
    __syncthreads();
    int stride = gridDim.x * 256;
    for (int e = blockIdx.x * 256 + t; e < E; e += stride) {
        int rep = (e >> SCHUNK_SH) & (NREP - 1);
        atomicAdd(&h[((dst[e] >> BSH) << 3) | rep], 1);
    }
    __syncthreads();
    for (int i = t; i < nb8; i += 256)
        if (h[i]) atomicAdd(&bcnt8[i], h[i]);
}

// ---- k2: exclusive scan of bcnt8[NB*8] -> bcur8 (absolute positions), bbase ----
__global__ __launch_bounds__(1024) void bucket_scan8_kernel(
        const int* __restrict__ bcnt8, int* __restrict__ bcur8,
        int* __restrict__ bbase, int NB, int E) {
    int t = threadIdx.x;
    int nb8 = NB * NREP;
    int base = t * 8;
    int v[8];
    #pragma unroll
    for (int i = 0; i < 8; ++i) v[i] = (base + i < nb8) ? bcnt8[base + i] : 0;
    int local = 0;
    #pragma unroll
    for (int i = 0; i < 8; ++i) local += v[i];
    int lane = t & 63, wv = t >> 6;
    int x = local;
    #pragma unroll
    for (int o = 1; o < 64; o <<= 1) {
        int y = __shfl_up(x, o);
        if (lane >= o) x += y;
    }
    __shared__ int wsum[16];
    if (lane == 63) wsum[wv] = x;
    __syncthreads();
    int woff = 0;
    for (int i = 0; i < wv; ++i) woff += wsum[i];
    int run = woff + x - local;
    #pragma unroll
    for (int i = 0; i < 8; ++i) {
        int g = base + i;
        if (g < nb8) {
            bcur8[g] = run;
            if ((g & (NREP - 1)) == 0) bbase[g >> 3] = run;
        }
        run += v[i];
    }
    if (t == 0) bbase[NB] = E;
}

// ---- k3: two-phase scatter of packed (src | dlocal<<25), bucket-major ----
__global__ __launch_bounds__(256) void bin_scatter_kernel(
        const int* __restrict__ src, const int* __restrict__ dst,
        int* __restrict__ bcur8, unsigned int* __restrict__ staged,
        int E, int NB) {
    __shared__ int lcnt[1024];
    __shared__ int lbase[1024];
    int t = threadIdx.x;
    int rep = blockIdx.x & (NREP - 1);
    int e0 = blockIdx.x << SCHUNK_SH;
    int e1 = min(e0 + SCHUNK, E);
    for (int i = t; i < NB; i += 256) lcnt[i] = 0;
    __syncthreads();
    for (int e = e0 + t; e < e1; e += 256)
        atomicAdd(&lcnt[dst[e] >> BSH], 1);
    __syncthreads();
    for (int i = t; i < NB; i += 256) {
        int c = lcnt[i];
        lbase[i] = c ? atomicAdd(&bcur8[(i << 3) | rep], c) : 0;
        lcnt[i] = 0;
    }
    __syncthreads();
    for (int e = e0 + t; e < e1; e += 256) {
        int s = src[e], d = dst[e];
        int b = d >> BSH, dl = d & (BNODES - 1);
        int pos = lbase[b] + atomicAdd(&lcnt[b], 1);
        staged[pos] = (unsigned int)s | ((unsigned int)dl << 25);
    }
}

// ---- k4: per-bucket finalize: row_ptr, dinv, csr_src ----
__global__ __launch_bounds__(256) void bucket_place_kernel(
        const unsigned int* __restrict__ staged, const int* __restrict__ bbase,
        int* __restrict__ row_ptr, float* __restrict__ dinv,
        int* __restrict__ csr_src, int N, int E) {
    int b = blockIdx.x;
    int t = threadIdx.x;
    int base = bbase[b], end = bbase[b + 1];
    __shared__ int cnt[BNODES];
    __shared__ int cur[BNODES];
    __shared__ int wsum2[2];
    if (t < BNODES) cnt[t] = 0;
    __syncthreads();
    for (int i = base + t; i < end; i += 256)
        atomicAdd(&cnt[staged[i] >> 25], 1);
    __syncthreads();

    bool act = t < BNODES;
    int v = act ? cnt[t] : 0;
    int lane = t & 63, wv = t >> 6;
    int x = v;
    #pragma unroll
    for (int o = 1; o < 64; o <<= 1) {
        int y = __shfl_up(x, o);
        if (lane >= o) x += y;
    }
    if (lane == 63 && wv == 0) wsum2[0] = x;
    __syncthreads();
    if (act) {
        int excl = x - v + (wv == 1 ? wsum2[0] : 0);
        int gnode = b * BNODES + t;
        int rp = base + excl;
        cur[t] = rp;
        if (gnode < N) {
            row_ptr[gnode] = rp;
            dinv[gnode] = rsqrtf((float)v + 1.0f);
        }
    }
    __syncthreads();
    for (int i = base + t; i < end; i += 256) {
        unsigned int u = staged[i];
        int dl = u >> 25;
        int p = atomicAdd(&cur[dl], 1);
        csr_src[p] = (int)(u & 0x1FFFFFFu);
    }
    if (b == 0 && t == 0) row_ptr[N] = E;
}

// ---- MFMA GEMM: Hs[N][128] = bf16( (X[N][128] @ W) * dinv[row] ) ----
template <bool IN_FP32>
__global__ __launch_bounds__(256) void mfma_gemm_kernel(
        const void* __restrict__ Xv, const __hip_bfloat16* __restrict__ Wt,
        const float* __restrict__ dinv, __hip_bfloat16* __restrict__ Y, int N) {
    __shared__ short Ws[FEAT][136];
    int t = threadIdx.x;
    for (int i = t; i < FEAT * 16; i += 256) {
        int n = i >> 4, c = i & 15;
        *(uint4*)&Ws[n][c * 8] = *(const uint4*)((const unsigned short*)Wt + n * FEAT + c * 8);
    }
    __syncthreads();

    int wave = t >> 6, lane = t & 63;
    int m = lane & 15, quad = lane >> 4;
    int rbase = (blockIdx.x * 4 + wave) * 16;
    if (rbase >= N) return;                 // wave-uniform
    int row = rbase + m;
    bool rok = row < N;

    f32x4 acc[8];
    #pragma unroll
    for (int nt = 0; nt < 8; ++nt) acc[nt] = (f32x4){0.f, 0.f, 0.f, 0.f};

    #pragma unroll
    for (int ks = 0; ks < 4; ++ks) {
        short8 a;
        if (IN_FP32) {
            const float* X = (const float*)Xv;
            float xs[8];
            if (rok) {
                float4 x0 = *(const float4*)(X + (size_t)row * FEAT + ks * 32 + quad * 8);
                float4 x1 = *(const float4*)(X + (size_t)row * FEAT + ks * 32 + quad * 8 + 4);
                xs[0] = x0.x; xs[1] = x0.y; xs[2] = x0.z; xs[3] = x0.w;
                xs[4] = x1.x; xs[5] = x1.y; xs[6] = x1.z; xs[7] = x1.w;
            } else {
                #pragma unroll
                for (int j = 0; j < 8; ++j) xs[j] = 0.f;
            }
            #pragma unroll
            for (int j = 0; j < 8; ++j) a[j] = (short)bf16_rn(xs[j]);
        } else {
            const unsigned short* X = (const unsigned short*)Xv;
            if (rok)
                a = *(const short8*)(X + (size_t)row * FEAT + ks * 32 + quad * 8);
            else {
                #pragma unroll
                for (int j = 0; j < 8; ++j) a[j] = 0;
            }
        }
        #pragma unroll
        for (int nt = 0; nt < 8; ++nt) {
            short8 bfr = *(const short8*)&Ws[nt * 16 + m][ks * 32 + quad * 8];
            acc[nt] = __builtin_amdgcn_mfma_f32_16x16x32_bf16(a, bfr, acc[nt], 0, 0, 0);
        }
    }

    float dr[4];
    #pragma unroll
    for (int r = 0; r < 4; ++r) {
        int ro = rbase + quad * 4 + r;
        dr[r] = (ro < N) ? dinv[ro] : 0.f;
    }
    unsigned short* Yo = (unsigned short*)Y;
    #pragma unroll
    for (int nt = 0; nt < 8; ++nt) {
        #pragma unroll
        for (int r = 0; r < 4; ++r) {
            int ro = rbase + quad * 4 + r;
            if (ro < N)
                Yo[(size_t)ro * FEAT + nt * 16 + m] = bf16_rn(acc[nt][r] * dr[r]);
        }
    }
}

// ---- fused CSR gather + MFMA epilogue (R17, byte-identical) ----
// Gather: 4 nodes/wave, 16 lanes x uint4/row, GDEPTH-deep. Block = 16
// nodes = one MFMA M-tile; rows land in LDS As[16][136]. B-fragments
// register-prefetched between As-write and barrier (straggler wait hides
// their latency).
//   EPI==1: 4 waves x 2 N-tiles of As@W2, scale by dinv, write bf16.
//   EPI==2: wave 0: As@Wout + bout, log_softmax, fp32 out.
template <int EPI>
__global__ __launch_bounds__(256, 4) void gather_fused_kernel(
        const int* __restrict__ row_ptr, const int* __restrict__ csr_src,
        const float* __restrict__ dinv, const __hip_bfloat16* __restrict__ Hs,
        const float* __restrict__ bias, const __hip_bfloat16* __restrict__ Wt,
        const float* __restrict__ bvec, void* __restrict__ outp, int N) {
    __shared__ short As[16][136];

    int t = threadIdx.x;
    int lane = t & 63;
    int wave = t >> 6;
    int grp = lane >> 4;                 // node group within wave, 0..3
    int fl = lane & 15;                  // uint4 index within 256B row
    int node = blockIdx.x * 16 + wave * 4 + grp;
    bool nok = node < N;
    int nd = nok ? node : 0;             // clamp for safe loads; write masked

    const char* Hb = (const char*)Hs;
    unsigned foff = (unsigned)fl << 4;

    // hoisted: self row, dinv, bias — in flight under the whole edge loop
    uint4 hu = *(const uint4*)(Hb + (((unsigned)nd << 8) + foff));
    float di = dinv[nd];
    float4 b0 = ((const float4*)bias)[fl * 2];
    float4 b1 = ((const float4*)bias)[fl * 2 + 1];

    float acc[8];
    #pragma unroll
    for (int i = 0; i < 8; ++i) acc[i] = 0.f;

    int j = row_ptr[nd], end = row_ptr[nd + 1];

    // main: GDEPTH rows per batch per group, 4*GDEPTH rows in flight per wave
    for (; j + GDEPTH <= end; j += GDEPTH) {
        unsigned off[GDEPTH];
        #pragma unroll
        for (int k = 0; k < GDEPTH; ++k)
            off[k] = ((unsigned)csr_src[j + k] << 8) + foff;
        uint4 u[GDEPTH];
        #pragma unroll
        for (int k = 0; k < GDEPTH; ++k)
            u[k] = *(const uint4*)(Hb + off[k]);
        #pragma unroll
        for (int k = 0; k < GDEPTH; ++k) {
            acc[0] += bf16_lo(u[k].x); acc[1] += bf16_hi(u[k].x);
            acc[2] += bf16_lo(u[k].y); acc[3] += bf16_hi(u[k].y);
            acc[4] += bf16_lo(u[k].z); acc[5] += bf16_hi(u[k].z);
            acc[6] += bf16_lo(u[k].w); acc[7] += bf16_hi(u[k].w);
        }
    }
    // tail: one predicated batch (loads clamped to first valid edge, adds gated)
    if (j < end) {
        int mm = end - j;                // 1..GDEPTH-1
        unsigned off[GDEPTH];
        #pragma unroll
        for (int k = 0; k < GDEPTH; ++k)
            off[k] = ((unsigned)csr_src[j + (k < mm ? k : 0)] << 8) + foff;
        uint4 u[GDEPTH];
        #pragma unroll
        for (int k = 0; k < GDEPTH; ++k)
            u[k] = *(const uint4*)(Hb + off[k]);
        #pragma unroll
        for (int k = 0; k < GDEPTH; ++k) {
            if (k < mm) {
                acc[0] += bf16_lo(u[k].x); acc[1] += bf16_hi(u[k].x);
                acc[2] += bf16_lo(u[k].y); acc[3] += bf16_hi(u[k].y);
                acc[4] += bf16_lo(u[k].z); acc[5] += bf16_hi(u[k].z);
                acc[6] += bf16_lo(u[k].w); acc[7] += bf16_hi(u[k].w);
            }
        }
    }

    // self-loop row
    acc[0] += bf16_lo(hu.x); acc[1] += bf16_hi(hu.x);
    acc[2] += bf16_lo(hu.y); acc[3] += bf16_hi(hu.y);
    acc[4] += bf16_lo(hu.z); acc[5] += bf16_hi(hu.z);
    acc[6] += bf16_lo(hu.w); acc[7] += bf16_hi(hu.w);

    float v0 = fmaxf(di * acc[0] + b0.x, 0.f);
    float v1 = fmaxf(di * acc[1] + b0.y, 0.f);
    float v2 = fmaxf(di * acc[2] + b0.z, 0.f);
    float v3 = fmaxf(di * acc[3] + b0.w, 0.f);
    float v4 = fmaxf(di * acc[4] + b1.x, 0.f);
    float v5 = fmaxf(di * acc[5] + b1.y, 0.f);
    float v6 = fmaxf(di * acc[6] + b1.z, 0.f);
    float v7 = fmaxf(di * acc[7] + b1.w, 0.f);

    uint4 o;
    o.x = (unsigned int)bf16_rn(v0) | ((unsigned int)bf16_rn(v1) << 16);
    o.y = (unsigned int)bf16_rn(v2) | ((unsigned int)bf16_rn(v3) << 16);
    o.z = (unsigned int)bf16_rn(v4) | ((unsigned int)bf16_rn(v5) << 16);
    o.w = (unsigned int)bf16_rn(v6) | ((unsigned int)bf16_rn(v7) << 16);

    // hand off this wave's 4 rows to the block A-tile (garbage rows masked
    // later: MFMA D-row m depends only on A-row m)
    *(uint4*)&As[wave * 4 + grp][fl * 8] = o;

    int m = lane & 15, quad = lane >> 4;
    int rbase0 = blockIdx.x * 16;
    const unsigned short* Wu = (const unsigned short*)Wt;

    if (EPI == 1) {
        // prefetch this lane's B-fragments + dinv BEFORE the barrier:
        // loads fly during the straggler wait, consumed from regs after.
        short8 bf[2][4];
        #pragma unroll
        for (int n2 = 0; n2 < 2; ++n2)
            #pragma unroll
            for (int ks = 0; ks < 4; ++ks)
                bf[n2][ks] = *(const short8*)(
                    Wu + ((wave * 2 + n2) * 16 + m) * FEAT + ks * 32 + quad * 8);
        float dr[4];
        #pragma unroll
        for (int r = 0; r < 4; ++r) {
            int ro = rbase0 + quad * 4 + r;
            dr[r] = (ro < N) ? dinv[ro] : 0.f;
        }
        __syncthreads();
        f32x4 acc2[2];
        #pragma unroll
        for (int n2 = 0; n2 < 2; ++n2) acc2[n2] = (f32x4){0.f, 0.f, 0.f, 0.f};
        #pragma unroll
        for (int ks = 0; ks < 4; ++ks) {
            short8 a = *(const short8*)&As[m][ks * 32 + quad * 8];
            #pragma unroll
            for (int n2 = 0; n2 < 2; ++n2)
                acc2[n2] = __builtin_amdgcn_mfma_f32_16x16x32_bf16(a, bf[n2][ks], acc2[n2], 0, 0, 0);
        }
        unsigned short* Yo = (unsigned short*)outp;
        #pragma unroll
        for (int r = 0; r < 4; ++r) {
            int ro = rbase0 + quad * 4 + r;
            if (ro < N) {
                #pragma unroll
                for (int n2 = 0; n2 < 2; ++n2)
                    Yo[(size_t)ro * FEAT + (wave * 2 + n2) * 16 + m] =
                        bf16_rn(acc2[n2][r] * dr[r]);
            }
        }
    } else {
        // wave 0 prefetches its 16 B-fragments + bias pre-barrier
        short8 bf[4][4];
        float bj[4];
        if (wave == 0) {
            #pragma unroll
            for (int nt = 0; nt < 4; ++nt)
                #pragma unroll
                for (int ks = 0; ks < 4; ++ks)
                    bf[nt][ks] = *(const short8*)(
                        Wu + (nt * 16 + m) * FEAT + ks * 32 + quad * 8);
            #pragma unroll
            for (int nt = 0; nt < 4; ++nt) bj[nt] = bvec[nt * 16 + m];
        }
        __syncthreads();
        if (wave == 0) {
            f32x4 acc4[4];
            #pragma unroll
            for (int nt = 0; nt < 4; ++nt) acc4[nt] = (f32x4){0.f, 0.f, 0.f, 0.f};
            #pragma unroll
            for (int ks = 0; ks < 4; ++ks) {
                short8 a = *(const short8*)&As[m][ks * 32 + quad * 8];
                #pragma unroll
                for (int nt = 0; nt < 4; ++nt)
                    acc4[nt] = __builtin_amdgcn_mfma_f32_16x16x32_bf16(a, bf[nt][ks], acc4[nt], 0, 0, 0);
            }
            float* out = (float*)outp;
            #pragma unroll
            for (int r = 0; r < 4; ++r) {
                int ro = rbase0 + quad * 4 + r;   // uniform within 16-lane group
                if (ro >= N) continue;
                float w0 = acc4[0][r] + bj[0];
                float w1 = acc4[1][r] + bj[1];
                float w2 = acc4[2][r] + bj[2];
                float w3 = acc4[3][r] + bj[3];
                float mx = fmaxf(fmaxf(w0, w1), fmaxf(w2, w3));
                #pragma unroll
                for (int os = 1; os <= 8; os <<= 1) mx = fmaxf(mx, __shfl_xor(mx, os));
                float s = __expf(w0 - mx) + __expf(w1 - mx) + __expf(w2 - mx) + __expf(w3 - mx);
                #pragma unroll
                for (int os = 1; os <= 8; os <<= 1) s += __shfl_xor(s, os);
                float ls = mx + __logf(s);
                float* op = out + (size_t)ro * OUTF + m;
                op[0]  = w0 - ls;
                op[16] = w1 - ls;
                op[32] = w2 - ls;
                op[48] = w3 - ls;
            }
        }
    }
}

extern "C" void kernel_launch(void* const* d_in, const int* in_sizes, int n_in,
                              void* d_out, int out_size, void* d_ws, size_t ws_size,
                              hipStream_t stream) {
    const float* x    = (const float*)d_in[0];
    const int*   ei   = (const int*)  d_in[1];
    const float* W1   = (const float*)d_in[2];
    const float* b1   = (const float*)d_in[3];
    const float* W2   = (const float*)d_in[4];
    const float* b2   = (const float*)d_in[5];
    const float* Wout = (const float*)d_in[6];
    const float* bout = (const float*)d_in[7];
    float* out = (float*)d_out;

    int N = in_sizes[0] / FEAT;
    int E = in_sizes[1] / 2;
    const int* srcp = ei;
    const int* dstp = ei + E;
    int NB = (N + BNODES - 1) >> BSH;   // <= 1024 for N <= 131072

    char* ws = (char*)d_ws;
    __hip_bfloat16* Bh   = (__hip_bfloat16*)ws;                   // N*128 bf16
    __hip_bfloat16* Ba   = Bh + (size_t)N * FEAT;                 // N*128 bf16
    __hip_bfloat16* W1t  = Ba + (size_t)N * FEAT;                 // 16384 bf16
    __hip_bfloat16* W2t  = W1t + FEAT * FEAT;                     // 16384 bf16
    __hip_bfloat16* WoutT = W2t + FEAT * FEAT;                    // 8192 bf16
    float* dinv    = (float*)(WoutT + OUTF * FEAT);               // N
    int*   rowp    = (int*)(dinv + N);                            // N+1
    int*   bcnt8   = rowp + N + 1;                                // 8192
    int*   bcur8   = bcnt8 + 8192;                                // 8192
    int*   bbase   = bcur8 + 8192;                                // NB+1
    unsigned int* staged = (unsigned int*)(bbase + 1032);         // E
    int*   csrsrc  = (int*)(staged + E);                          // E

    // k0: convert weights + zero bcnt8 (replaces memset dispatch)
    convw_kernel<<<192, 256, 0, stream>>>(
        W1, W2, Wout, W1t, W2t, WoutT, bcnt8);
    bincount8_kernel<<<256, 256, 0, stream>>>(dstp, bcnt8, E, NB);
    bucket_scan8_kernel<<<1, 1024, 0, stream>>>(bcnt8, bcur8, bbase, NB, E);
    bin_scatter_kernel<<<(E + SCHUNK - 1) / SCHUNK, 256, 0, stream>>>(
        srcp, dstp, bcur8, staged, E, NB);
    bucket_place_kernel<<<NB, 256, 0, stream>>>(staged, bbase, rowp, dinv, csrsrc, N, E);

    int ggrid = (N + 63) / 64;
    int agrid = (N + 15) / 16;

    // Layer 1 GEMM: Bh = (x @ W1) * dinv   (bf16, prescaled)
    mfma_gemm_kernel<true><<<ggrid, 256, 0, stream>>>(x, W1t, dinv, Bh, N);

    // Layer 1 gather + Layer 2 GEMM fused: Ba = ((relu(gather(Bh))+b1) @ W2) * dinv
    gather_fused_kernel<1><<<agrid, 256, 0, stream>>>(
        rowp, csrsrc, dinv, Bh, b1, W2t, nullptr, Ba, N);

    // Layer 2 gather + output layer + log_softmax fused
    gather_fused_kernel<2><<<agrid, 256, 0, stream>>>(
        rowp, csrsrc, dinv, Ba, b2, WoutT, bout, out, N);
}